// Round 1
// baseline (333.918 us; speedup 1.0000x reference)
//
#include <hip/hip_runtime.h>

// WarpLayer: bilinear backward warp.
// image [B,H,W,C] f32, flow [B,H,W,2] f32 -> out [B,H,W,C] f32
// q = grid - flow; y0 = clip(floor(qy),0,H-2); alpha = clip(q - floor_clipped, 0, 1)
// out = lerp over 4 corners.
//
// Layout choice: C=32 innermost => each corner pixel = 128 contiguous bytes.
// One thread handles one float4 channel-group (8 threads per pixel), so a
// 64-lane wave covers 8 pixels with coalesced 16B/lane loads and stores.

#define WB 8
#define WH 384
#define WW 512
#define WC 32

__global__ __launch_bounds__(256) void warp_kernel(
    const float* __restrict__ image,
    const float* __restrict__ flow,
    float* __restrict__ out)
{
    const int tid = blockIdx.x * blockDim.x + threadIdx.x;
    const int npix = WB * WH * WW;
    const int cg  = tid & 7;   // channel group: float4 index within the 32 channels
    const int pix = tid >> 3;  // linear pixel index b*H*W + h*W + w
    if (pix >= npix) return;

    const int w   = pix % WW;
    const int bh  = pix / WW;
    const int h   = bh % WH;
    const int b   = bh / WH;

    // flow[..,0] = dy, flow[..,1] = dx ; q = grid - flow
    const float2 f = ((const float2*)flow)[pix];
    const float qy = (float)h - f.x;
    const float qx = (float)w - f.y;

    const float fly = fminf(fmaxf(floorf(qy), 0.0f), (float)(WH - 2));
    const float flx = fminf(fmaxf(floorf(qx), 0.0f), (float)(WW - 2));
    const int y0 = (int)fly;
    const int x0 = (int)flx;
    const float ay = fminf(fmaxf(qy - fly, 0.0f), 1.0f);
    const float ax = fminf(fmaxf(qx - flx, 0.0f), 1.0f);

    // float4-unit indices: pixel p has 8 float4 groups
    const float4* __restrict__ img4 = (const float4*)image;
    const long base = ((long)b * WH * WW + (long)y0 * WW + x0) * 8 + cg;
    const float4 tl = img4[base];
    const float4 tr = img4[base + 8];            // x0+1
    const float4 bl = img4[base + (long)WW * 8]; // y0+1
    const float4 br = img4[base + (long)WW * 8 + 8];

    float4 r;
    {
        const float tx = ax * (tr.x - tl.x) + tl.x;
        const float bx = ax * (br.x - bl.x) + bl.x;
        r.x = ay * (bx - tx) + tx;
    }
    {
        const float ty = ax * (tr.y - tl.y) + tl.y;
        const float by = ax * (br.y - bl.y) + bl.y;
        r.y = ay * (by - ty) + ty;
    }
    {
        const float tz = ax * (tr.z - tl.z) + tl.z;
        const float bz = ax * (br.z - bl.z) + bl.z;
        r.z = ay * (bz - tz) + tz;
    }
    {
        const float tw = ax * (tr.w - tl.w) + tl.w;
        const float bw = ax * (br.w - bl.w) + bl.w;
        r.w = ay * (bw - tw) + tw;
    }

    ((float4*)out)[(long)pix * 8 + cg] = r;
}

extern "C" void kernel_launch(void* const* d_in, const int* in_sizes, int n_in,
                              void* d_out, int out_size, void* d_ws, size_t ws_size,
                              hipStream_t stream)
{
    const float* image = (const float*)d_in[0];
    const float* flow  = (const float*)d_in[1];
    float* out = (float*)d_out;

    const int nthreads = WB * WH * WW * (WC / 4); // 12,582,912
    const int block = 256;
    const int grid = (nthreads + block - 1) / block;
    warp_kernel<<<grid, block, 0, stream>>>(image, flow, out);
}